// Round 2
// baseline (743.959 us; speedup 1.0000x reference)
//
#include <hip/hip_runtime.h>
#include <math.h>

#define IMG 64
#define NPX 4096   // IMG*IMG
#define NC  16

typedef float v4f __attribute__((ext_vector_type(4)));

// ---------------------------------------------------------------------------
// Repack OIHW conv weights to [ci*25+tap][co] so the inner co-run is 16
// contiguous floats at a wave-uniform address -> s_load_dwordx16.
// wl0: 400 floats, wl1/wl2: 6400 floats each.
// ---------------------------------------------------------------------------
__global__ void repack_kernel(const float* __restrict__ w0,
                              const float* __restrict__ w1,
                              const float* __restrict__ w2,
                              float* __restrict__ wl0,
                              float* __restrict__ wl1,
                              float* __restrict__ wl2) {
    int idx = blockIdx.x * 256 + threadIdx.x;
    if (idx < 400) {
        int tap = idx >> 4, co = idx & 15;
        wl0[idx] = w0[co * 25 + tap];
    } else if (idx < 6800) {
        int e = idx - 400;
        int k = e >> 4, co = e & 15;          // k = ci*25 + tap
        wl1[e] = w1[co * 400 + k];
    } else if (idx < 13200) {
        int e = idx - 6800;
        int k = e >> 4, co = e & 15;
        wl2[e] = w2[co * 400 + k];
    }
}

// ---------------------------------------------------------------------------
// conv0: 1 input channel -> 16 output channels, 'same' 5x5.
// grid (32 strips, 8 batch), 128 threads; each thread = 1 pixel, 16 co.
// Output layout y0[b][co][p] (channel-first, matches coupling needs).
// ---------------------------------------------------------------------------
__global__ void conv0_kernel(const float* __restrict__ x,   // [8][4096]
                             const float* __restrict__ wl0, // [25][16]
                             const float* __restrict__ b0,  // [16]
                             float* __restrict__ y0) {      // [8][16][4096]
    __shared__ float tile[6 * 68];
    const int strip = blockIdx.x, b = blockIdx.y;
    const int r0 = strip * 2;
    const int tid = threadIdx.x;
    for (int f = tid; f < 6 * 68; f += 128) {
        int row = f / 68, col = f - row * 68;
        int gr = r0 - 2 + row, gc = col - 2;
        float v = 0.f;
        if (gr >= 0 && gr < IMG && gc >= 0 && gc < IMG)
            v = x[b * NPX + gr * IMG + gc];
        tile[f] = v;
    }
    __syncthreads();
    const int ri = tid >> 6, col = tid & 63;
    float acc[16];
#pragma unroll
    for (int co = 0; co < 16; ++co) acc[co] = b0[co];
#pragma unroll
    for (int kh = 0; kh < 5; ++kh) {
        float v[5];
#pragma unroll
        for (int kw = 0; kw < 5; ++kw) v[kw] = tile[(ri + kh) * 68 + col + kw];
#pragma unroll
        for (int kw = 0; kw < 5; ++kw) {
#pragma unroll
            for (int co = 0; co < 16; ++co)
                acc[co] = fmaf(wl0[(kh * 5 + kw) * 16 + co], v[kw], acc[co]);
        }
    }
    const int p = (r0 + ri) * IMG + col;
#pragma unroll
    for (int co = 0; co < 16; ++co)
        y0[(b * 16 + co) * NPX + p] = acc[co];
}

// ---------------------------------------------------------------------------
// conv16: 16 -> 16 channels, 'same' 5x5. grid (32,8), 128 threads.
// DO_STATS=true: fused epilogue computes per-pixel channel mean/std(ddof=1)
// and stores z[c] = (y[c]-m) / (s*sqrt(16))  -> coupling = z_i . z_j * mask.
// Weights read at wave-uniform addresses -> SGPR loads, no LDS/VALU cost.
// ---------------------------------------------------------------------------
template <bool DO_STATS>
__global__ void conv16_kernel(const float* __restrict__ yin,  // [8][16][4096]
                              const float* __restrict__ wl,   // [400][16]
                              const float* __restrict__ bias, // [16]
                              float* __restrict__ yout) {     // [8][16][4096]
    __shared__ float tile[16 * 6 * 68];  // [ci][row][col], cols conflict-free
    const int strip = blockIdx.x, b = blockIdx.y;
    const int r0 = strip * 2;
    const int tid = threadIdx.x;
    for (int f = tid; f < 16 * 408; f += 128) {
        int ci = f / 408;
        int rem = f - ci * 408;
        int row = rem / 68, col = rem - row * 68;
        int gr = r0 - 2 + row, gc = col - 2;
        float v = 0.f;
        if (gr >= 0 && gr < IMG && gc >= 0 && gc < IMG)
            v = yin[(b * 16 + ci) * NPX + gr * IMG + gc];
        tile[f] = v;
    }
    __syncthreads();
    const int ri = tid >> 6, col = tid & 63;
    float acc[16];
#pragma unroll
    for (int co = 0; co < 16; ++co) acc[co] = bias[co];
    for (int ci = 0; ci < 16; ++ci) {
        const float* tci = &tile[ci * 408];
        const float* wci = &wl[ci * 25 * 16];
#pragma unroll
        for (int kh = 0; kh < 5; ++kh) {
            float v[5];
#pragma unroll
            for (int kw = 0; kw < 5; ++kw) v[kw] = tci[(ri + kh) * 68 + col + kw];
#pragma unroll
            for (int kw = 0; kw < 5; ++kw) {
#pragma unroll
                for (int co = 0; co < 16; ++co)
                    acc[co] = fmaf(wci[(kh * 5 + kw) * 16 + co], v[kw], acc[co]);
            }
        }
    }
    const int p = (r0 + ri) * IMG + col;
    if (DO_STATS) {
        float m = 0.f;
#pragma unroll
        for (int co = 0; co < 16; ++co) m += acc[co];
        m *= (1.f / 16.f);
        float var = 0.f;
#pragma unroll
        for (int co = 0; co < 16; ++co) {
            float d = acc[co] - m;
            var = fmaf(d, d, var);
        }
        var *= (1.f / 15.f);                 // unbiased (torch.std / ddof=1)
        float inv = 0.25f / sqrtf(var);      // 1/(s*sqrt(C)), sqrt(16)=4
#pragma unroll
        for (int co = 0; co < 16; ++co)
            yout[(b * 16 + co) * NPX + p] = (acc[co] - m) * inv;
    } else {
#pragma unroll
        for (int co = 0; co < 16; ++co)
            yout[(b * 16 + co) * NPX + p] = acc[co];
    }
}

// ---------------------------------------------------------------------------
// coupling: out[b,i,j] = (sum_c z[b,c,i]*z[b,c,j]) * mask[i,j]
// grid (4 j-tiles, 256 i-tiles), 256 threads.
// Block tile: 16 i-rows x 1024 j-cols x all 8 batches (mask read once/tile).
// Thread: 4 consecutive j (v4f), zj frags in regs, zi broadcast from LDS.
// Stores are nontemporal: 536 MB streaming writes must not evict z/mask L2.
// ---------------------------------------------------------------------------
__global__ void coupling_kernel(const float* __restrict__ z,    // [8][16][4096]
                                const float* __restrict__ mask, // [4096][4096]
                                float* __restrict__ out) {      // [8][4096][4096]
    __shared__ float zis[8 * 16 * 16];  // [b][ii][c], 64B-aligned rows
    const int tid = threadIdx.x;
    const int j0 = blockIdx.x * 1024 + tid * 4;
    const int i0 = blockIdx.y * 16;
    for (int f = tid; f < 2048; f += 256) {
        int c = f & 15, ii = (f >> 4) & 15, b = f >> 8;
        zis[f] = z[(b * 16 + c) * NPX + i0 + ii];
    }
    __syncthreads();
    for (int b = 0; b < 8; ++b) {
        v4f zj[16];
#pragma unroll
        for (int c = 0; c < 16; ++c)
            zj[c] = *(const v4f*)&z[(b * 16 + c) * NPX + j0];
#pragma unroll 4
        for (int ii = 0; ii < 16; ++ii) {
            const v4f mv = *(const v4f*)&mask[(size_t)(i0 + ii) * NPX + j0];
            const float* zr = &zis[(b * 16 + ii) * 16];
            v4f a = (v4f)(0.f);
#pragma unroll
            for (int c = 0; c < 16; ++c) {
                float s = zr[c];
                a.x = fmaf(s, zj[c].x, a.x);
                a.y = fmaf(s, zj[c].y, a.y);
                a.z = fmaf(s, zj[c].z, a.z);
                a.w = fmaf(s, zj[c].w, a.w);
            }
            a *= mv;
            __builtin_nontemporal_store(a,
                (v4f*)&out[((size_t)(b * NPX + i0 + ii)) * NPX + j0]);
        }
    }
}

extern "C" void kernel_launch(void* const* d_in, const int* in_sizes, int n_in,
                              void* d_out, int out_size, void* d_ws, size_t ws_size,
                              hipStream_t stream) {
    const float* x    = (const float*)d_in[0];
    const float* w0   = (const float*)d_in[1];
    const float* b0   = (const float*)d_in[2];
    const float* w1   = (const float*)d_in[3];
    const float* b1   = (const float*)d_in[4];
    const float* w2   = (const float*)d_in[5];
    const float* b2   = (const float*)d_in[6];
    const float* mask = (const float*)d_in[7];
    float* out = (float*)d_out;
    float* ws  = (float*)d_ws;

    // workspace layout (floats), 4KB-aligned chunks; total ~6.4 MB
    float* wl0 = ws;                       // 400   (padded to 1024)
    float* wl1 = ws + 1024;                // 6400
    float* wl2 = ws + 8192;                // 6400  (padded to 16384 total)
    float* y0  = ws + 16384;               // 8*16*4096 = 524288
    float* y1  = y0 + 524288;
    float* zz  = y1 + 524288;

    repack_kernel<<<52, 256, 0, stream>>>(w0, w1, w2, wl0, wl1, wl2);
    conv0_kernel<<<dim3(32, 8), 128, 0, stream>>>(x, wl0, b0, y0);
    conv16_kernel<false><<<dim3(32, 8), 128, 0, stream>>>(y0, wl1, b1, y1);
    conv16_kernel<true><<<dim3(32, 8), 128, 0, stream>>>(y1, wl2, b2, zz);
    coupling_kernel<<<dim3(4, 256), 256, 0, stream>>>(zz, mask, out);
}